// Round 1
// baseline (25.205 us; speedup 1.0000x reference)
//
#include <hip/hip_runtime.h>

// Problem constants (from reference): B=32, S=1024, D=768, W=512
#define BB 32
#define SS 1024
#define DD 768
#define WW 512

// One block per (b, w) word. 192 threads = D/4 float4 lanes (3 waves).
// Each thread reads 1-2 float4 from the embedding span and writes one float4.
__global__ __launch_bounds__(192) void word_mean_kernel(
    const float* __restrict__ emb,     // [B, S, D] float32
    const int*   __restrict__ offsets, // [B, W, 2] int32 (JAX x64 disabled -> int32)
    const int*   __restrict__ mask,    // [B, W]    int32
    float*       __restrict__ out)     // [B, W, D] float32
{
    const int word = blockIdx.x;          // b*W + w
    const int b    = word >> 9;           // word / 512
    const int d4   = threadIdx.x;         // 0..191 (float4 lane)

    const int st = offsets[word * 2 + 0];
    const int ed = offsets[word * 2 + 1];
    const int m  = mask[word];
    const int len = ed - st;

    float4 r = make_float4(0.f, 0.f, 0.f, 0.f);
    if (m != 0 && len > 0) {
        const float4* row0 =
            (const float4*)(emb + ((size_t)b * SS + st) * DD) + d4;
        r = *row0;
        if (len == 2) {
            const float4 r1 =
                *((const float4*)(emb + ((size_t)b * SS + st + 1) * DD) + d4);
            r.x += r1.x; r.y += r1.y; r.z += r1.z; r.w += r1.w;
        }
        const float inv = 1.0f / (float)len;
        r.x *= inv; r.y *= inv; r.z *= inv; r.w *= inv;
    }
    ((float4*)(out + (size_t)word * DD))[d4] = r;
}

extern "C" void kernel_launch(void* const* d_in, const int* in_sizes, int n_in,
                              void* d_out, int out_size, void* d_ws, size_t ws_size,
                              hipStream_t stream) {
    const float* emb     = (const float*)d_in[0];
    const int*   offsets = (const int*)d_in[1];
    const int*   mask    = (const int*)d_in[2];
    float*       out     = (float*)d_out;

    dim3 grid(BB * WW);   // 16384 blocks, one per word
    dim3 block(192);      // D/4 float4 lanes
    hipLaunchKernelGGL(word_mean_kernel, grid, block, 0, stream,
                       emb, offsets, mask, out);
}

// Round 2
// 23.878 us; speedup vs baseline: 1.0555x; 1.0555x over previous
//
#include <hip/hip_runtime.h>

// Problem constants (from reference): B=32, S=1024, D=768, W=512
#define BB 32
#define SS 1024
#define DD 768
#define WW 512

// One 64-lane wave per word; each lane handles 3 float4 (64*3*4 = 768 floats).
// 256-thread blocks -> 4 words per block, grid = B*W/4 = 4096 blocks.
// Per wave: up to 6 independent coalesced 1-KiB loads + 3 stores (high MLP).
__global__ __launch_bounds__(256) void word_mean_kernel(
    const float* __restrict__ emb,     // [B, S, D] float32
    const int*   __restrict__ offsets, // [B, W, 2] int32 (JAX x64 disabled -> int32)
    const int*   __restrict__ mask,    // [B, W]    int32
    float*       __restrict__ out)     // [B, W, D] float32
{
    const int wave = threadIdx.x >> 6;              // 0..3
    const int lane = threadIdx.x & 63;
    const int word = (blockIdx.x << 2) + wave;      // 0..B*W-1
    const int b    = word >> 9;                     // word / W

    const int st  = offsets[word * 2 + 0];
    const int ed  = offsets[word * 2 + 1];
    const int m   = mask[word];
    const int len = ed - st;

    float4 r0 = make_float4(0.f, 0.f, 0.f, 0.f);
    float4 r1 = r0, r2 = r0;

    if (m != 0 && len > 0) {
        const float4* p0 = (const float4*)(emb + ((size_t)b * SS + st) * DD);
        r0 = p0[lane];
        r1 = p0[lane + 64];
        r2 = p0[lane + 128];
        if (len == 2) {
            const float4* p1 = p0 + (DD / 4);
            const float4 a0 = p1[lane];
            const float4 a1 = p1[lane + 64];
            const float4 a2 = p1[lane + 128];
            r0.x += a0.x; r0.y += a0.y; r0.z += a0.z; r0.w += a0.w;
            r1.x += a1.x; r1.y += a1.y; r1.z += a1.z; r1.w += a1.w;
            r2.x += a2.x; r2.y += a2.y; r2.z += a2.z; r2.w += a2.w;
            r0.x *= 0.5f; r0.y *= 0.5f; r0.z *= 0.5f; r0.w *= 0.5f;
            r1.x *= 0.5f; r1.y *= 0.5f; r1.z *= 0.5f; r1.w *= 0.5f;
            r2.x *= 0.5f; r2.y *= 0.5f; r2.z *= 0.5f; r2.w *= 0.5f;
        }
    }

    float4* o = (float4*)(out + (size_t)word * DD);
    o[lane]       = r0;
    o[lane + 64]  = r1;
    o[lane + 128] = r2;
}

extern "C" void kernel_launch(void* const* d_in, const int* in_sizes, int n_in,
                              void* d_out, int out_size, void* d_ws, size_t ws_size,
                              hipStream_t stream) {
    const float* emb     = (const float*)d_in[0];
    const int*   offsets = (const int*)d_in[1];
    const int*   mask    = (const int*)d_in[2];
    float*       out     = (float*)d_out;

    dim3 grid((BB * WW) / 4);  // 4096 blocks
    dim3 block(256);           // 4 waves = 4 words per block
    hipLaunchKernelGGL(word_mean_kernel, grid, block, 0, stream,
                       emb, offsets, mask, out);
}